// Round 11
// baseline (521.126 us; speedup 1.0000x reference)
//
#include <hip/hip_runtime.h>
#include <math.h>
#include <stdint.h>

#define NB 16
#define NC 256
#define NN 4096
#define ND 32

typedef __bf16 bf16_t;
typedef __bf16 bf16x4 __attribute__((ext_vector_type(4)));
typedef __bf16 bf16x8 __attribute__((ext_vector_type(8)));
typedef float  f32x4  __attribute__((ext_vector_type(4)));

#define AS_GLOBAL __attribute__((address_space(1)))
#define AS_LDS    __attribute__((address_space(3)))

// ---------------------------------------------------------------------------
// Kernel 0: convert weights to bf16 (+ lo residuals for q/k rows).
// Wq rows pre-scaled by log2(e) so attention uses exp2 directly.
// ---------------------------------------------------------------------------
__global__ __launch_bounds__(256) void wconv(
    const float* __restrict__ Wq, const float* __restrict__ Wk,
    const float* __restrict__ Wv, bf16_t* __restrict__ Wb, bf16_t* __restrict__ Wlo)
{
    int i = blockIdx.x * 256 + threadIdx.x;
    if (i >= 320 * 256) return;
    int row = i >> 8, c = i & 255;
    float v;
    if (row < 256)      v = Wv[(row      ) * 256 + c];
    else if (row < 288) v = Wq[(row - 256) * 256 + c] * 1.44269504088896340736f;
    else                v = Wk[(row - 288) * 256 + c];
    bf16_t h = (bf16_t)v;
    Wb[i] = h;
    if (row >= 256) Wlo[(row - 256) * 256 + c] = (bf16_t)(v - (float)h);
}

// ---------------------------------------------------------------------------
// Kernel 1: fused q/k/v projection as one MFMA GEMM (unchanged, ~8 us).
// ---------------------------------------------------------------------------
#define BN_P  128
#define KSTEP 64
#define XPAD  130

__global__ __launch_bounds__(512) void proj_mfma(
    const float* __restrict__ x, const bf16_t* __restrict__ Wb,
    const bf16_t* __restrict__ Wlo,
    bf16_t* __restrict__ Pqb, bf16_t* __restrict__ Pkb, bf16_t* __restrict__ Vn)
{
    __shared__ float xt[KSTEP][XPAD];

    const int b  = blockIdx.x >> 5;
    const int n0 = (blockIdx.x & 31) * BN_P;
    const int tid  = threadIdx.x;
    const int lane = tid & 63;
    const int w    = tid >> 6;
    const int mstrip = w >> 1;
    const int nh     = w & 1;
    const int llo = lane & 15, lhi = lane >> 4;
    const bool qkwave = (mstrip == 3);

    const float* xb = x + (size_t)b * NC * NN + n0;

    f32x4 acc[5][4];
    #pragma unroll
    for (int mf = 0; mf < 5; ++mf)
        #pragma unroll
        for (int nf = 0; nf < 4; ++nf)
            acc[mf][nf] = (f32x4){0.f,0.f,0.f,0.f};

    for (int k0 = 0; k0 < NC; k0 += KSTEP) {
        #pragma unroll
        for (int p = 0; p < 4; ++p) {
            int idx = p * 512 + tid;
            int c   = idx >> 5;
            int nn  = (idx & 31) << 2;
            float4 v = *(const float4*)(xb + (size_t)(k0 + c) * NN + nn);
            *(float2*)&xt[c][nn]     = make_float2(v.x, v.y);
            *(float2*)&xt[c][nn + 2] = make_float2(v.z, v.w);
        }
        __syncthreads();

        #pragma unroll
        for (int ks = 0; ks < 2; ++ks) {
            bf16x8 Ah[5], Al[4];
            #pragma unroll
            for (int mf = 0; mf < 5; ++mf) {
                int row = mstrip * 80 + mf * 16 + llo;
                Ah[mf] = *(const bf16x8*)(Wb + (size_t)row * NC + k0 + ks * 32 + lhi * 8);
            }
            if (qkwave) {
                #pragma unroll
                for (int mf = 1; mf < 5; ++mf) {
                    int row = mstrip * 80 + mf * 16 + llo;
                    Al[mf-1] = *(const bf16x8*)(Wlo + (size_t)(row - 256) * NC
                                                + k0 + ks * 32 + lhi * 8);
                }
            }

            #pragma unroll
            for (int nf = 0; nf < 4; ++nf) {
                const int n  = nh * 64 + nf * 16 + llo;
                const int cb = ks * 32 + lhi * 8;
                bf16x8 bh, bl;
                #pragma unroll
                for (int j = 0; j < 8; ++j) {
                    float f = xt[cb + j][n];
                    bf16_t h = (bf16_t)f;
                    bh[j] = h;
                    if (qkwave) bl[j] = (bf16_t)(f - (float)h);
                }
                #pragma unroll
                for (int mf = 0; mf < 5; ++mf)
                    acc[mf][nf] = __builtin_amdgcn_mfma_f32_16x16x32_bf16(
                                      Ah[mf], bh, acc[mf][nf], 0, 0, 0);
                if (qkwave) {
                    #pragma unroll
                    for (int mf = 1; mf < 5; ++mf) {
                        acc[mf][nf] = __builtin_amdgcn_mfma_f32_16x16x32_bf16(
                                          Al[mf-1], bh, acc[mf][nf], 0, 0, 0);
                        acc[mf][nf] = __builtin_amdgcn_mfma_f32_16x16x32_bf16(
                                          Ah[mf], bl, acc[mf][nf], 0, 0, 0);
                    }
                }
            }
        }
        __syncthreads();
    }

    #pragma unroll
    for (int mf = 0; mf < 5; ++mf) {
        const int rowbase = mstrip * 80 + mf * 16 + lhi * 4;
        #pragma unroll
        for (int nf = 0; nf < 4; ++nf) {
            const int n = n0 + nh * 64 + nf * 16 + llo;
            if (rowbase < 256) {
                #pragma unroll
                for (int r = 0; r < 4; ++r)
                    Vn[((size_t)b * NC + rowbase + r) * NN + n] = (bf16_t)acc[mf][nf][r];
            } else {
                const int d = rowbase - 256;
                bf16x4 q4;
                #pragma unroll
                for (int r = 0; r < 4; ++r) q4[r] = (bf16_t)acc[mf][nf][r];
                if (d < 32) *(bf16x4*)(Pqb + ((size_t)b * NN + n) * ND + d) = q4;
                else        *(bf16x4*)(Pkb + ((size_t)b * NN + n) * ND + d - 32) = q4;
            }
        }
    }
}

// ---------------------------------------------------------------------------
// Kernel 2: GEMM-shaped attention, counted-vmcnt raw-barrier pipeline (T3/T4).
// Block = (batch, 256-m chunk), 8 waves, 128 KB LDS, 1 block/CU.
// Body t:  loadK(t+2)->kb[alt]                       (stays in flight across bar)
//          s_waitcnt vmcnt(4)                        (drains stage(t) only)
//          s_waitcnt lgkmcnt(0); s_barrier; sched(0)
//          stageV(t+1) DMA -> vlds[(t+1)&1]          (post-bar: safe vs pv(t-1))
//          qk(t+1) -> plds[(t+1)&1]                  (post-bar: safe vs pv(t-1))
//          pv(t) reads vlds/plds[t&1]                (stage(t) drained by ALL
//                                                     waves pre-barrier)
// Loop unrolled x2 so all buffer indices are compile-time constants.
// ---------------------------------------------------------------------------
__global__ __launch_bounds__(512, 2) void attn_mfma(
    const bf16_t* __restrict__ Pqb,   // keys    K [B][N][32]
    const bf16_t* __restrict__ Pkb,   // queries Q [B][N][32] (pre-scaled log2e)
    const bf16_t* __restrict__ Vn,    // V [B][C][N]
    const float* __restrict__ x,
    const float* __restrict__ gamma_p,
    float* __restrict__ y)
{
    __shared__ bf16_t vlds[2][256*64];    // 64 KB V tiles, swizzled
    __shared__ bf16_t plds[2][256*64];    // 64 KB P tiles, swizzled

    const int wg  = blockIdx.x;
    const int swb = (wg & 7) * 32 + (wg >> 3);
    const int b   = swb >> 4;
    const int m0  = (swb & 15) << 8;

    const int tid  = threadIdx.x;
    const int lane = tid & 63;
    const int w    = tid >> 6;            // 0..7
    const int lhi  = lane >> 4;
    const int llo  = lane & 15;
    const int wc   = w & 3;               // PV m-quarter
    const int eh   = w >> 2;              // PV e-half

    const bf16_t* Kbase = Pqb + (size_t)b * NN * ND;
    const bf16_t* Vball = Vn  + (size_t)b * NC * NN;

    bf16x8 qa[2];
    #pragma unroll
    for (int mq = 0; mq < 2; ++mq)
        qa[mq] = *(const bf16x8*)(Pkb + ((size_t)(b*NN + m0 + w*32 + mq*16 + llo)) * ND + lhi*8);

    f32x4 acc[8][4];                      // [et][mt]
    #pragma unroll
    for (int et = 0; et < 8; ++et)
        #pragma unroll
        for (int mt = 0; mt < 4; ++mt)
            acc[et][mt] = (f32x4){0.f,0.f,0.f,0.f};

    float ps[2] = {0.f, 0.f};
    bf16x8 kbA[4], kbB[4];                // double-buffered K frags
    const int swz = (llo & 7) << 4;

    const int r8  = lane >> 3;
    const int nsw = 8 * ((lane & 7) ^ r8);
    auto stageV = [&](int tt, int bufw) {
        #pragma unroll
        for (int i = 0; i < 4; ++i) {
            const int row0 = w*32 + i*8;
            const bf16_t* src = Vball + (size_t)(row0 + r8) * NN + tt*64 + nsw;
            bf16_t* dst = &vlds[bufw][row0 * 64];
            __builtin_amdgcn_global_load_lds(
                (const AS_GLOBAL unsigned int*)src,
                (AS_LDS unsigned int*)dst, 16, 0, 0);
        }
    };

    auto loadKinto = [&](int tt, bf16x8* kb) {
        #pragma unroll
        for (int nt = 0; nt < 4; ++nt)
            kb[nt] = *(const bf16x8*)(Kbase + (size_t)(tt*64 + nt*16 + llo) * ND + lhi*8);
    };

    auto qk_phase = [&](const bf16x8* kb, int bufw) {
        f32x4 s[4][2];
        #pragma unroll
        for (int nt = 0; nt < 4; ++nt)
            #pragma unroll
            for (int mq = 0; mq < 2; ++mq)
                s[nt][mq] = __builtin_amdgcn_mfma_f32_16x16x32_bf16(kb[nt], qa[mq],
                                (f32x4){0.f,0.f,0.f,0.f}, 0, 0, 0);
        char* base = (char*)&plds[bufw][0] + (size_t)(w*32 + llo) * 128;
        #pragma unroll
        for (int mq = 0; mq < 2; ++mq)
            #pragma unroll
            for (int nt = 0; nt < 4; ++nt) {
                bf16x4 q4;
                #pragma unroll
                for (int r = 0; r < 4; ++r) {
                    float p = __builtin_amdgcn_exp2f(s[nt][mq][r]);
                    ps[mq] += p;
                    q4[r] = (bf16_t)p;
                }
                *(bf16x4*)(base + mq*2048 + ((nt*32 + lhi*8) ^ swz)) = q4;
            }
    };

    auto pv_phase = [&](int bufw) {
        char* vb = (char*)&vlds[bufw][0];
        char* pb = (char*)&plds[bufw][0];
        #pragma unroll
        for (int ks = 0; ks < 2; ++ks) {
            const int cofs = (ks*64 + lhi*16) ^ swz;
            bf16x8 pf[4];
            #pragma unroll
            for (int mt = 0; mt < 4; ++mt) {
                const int row = wc*64 + mt*16 + llo;
                pf[mt] = *(const bf16x8*)(pb + (size_t)row*128 + cofs);
            }
            bf16x8 va[8];
            #pragma unroll
            for (int ei = 0; ei < 8; ++ei) {
                const int row = eh*128 + ei*16 + llo;
                va[ei] = *(const bf16x8*)(vb + (size_t)row*128 + cofs);
            }
            __builtin_amdgcn_s_setprio(1);
            #pragma unroll
            for (int ei = 0; ei < 8; ++ei)
                #pragma unroll
                for (int mt = 0; mt < 4; ++mt)
                    acc[ei][mt] = __builtin_amdgcn_mfma_f32_16x16x32_bf16(
                                      va[ei], pf[mt], acc[ei][mt], 0, 0, 0);
            __builtin_amdgcn_s_setprio(0);
        }
    };

    // ---- prologue: K(0)->A, V(0) DMA, K(1)->B, P(0)
    loadKinto(0, kbA);
    stageV(0, 0);
    loadKinto(1, kbB);
    qk_phase(kbA, 0);       // auto-waits K(0); stage(0)+K(1) stay in flight

    // ---- main loop, unrolled x2 (compile-time buffer indices)
    for (int t = 0; t < NN/64; t += 2) {
        // even sub-body: pv(t) on buffers 0
        if (t + 2 < NN/64) loadKinto(t + 2, kbA);
        if (t < NN/64 - 2) asm volatile("s_waitcnt vmcnt(4)" ::: "memory");
        else               asm volatile("s_waitcnt vmcnt(0)" ::: "memory");
        asm volatile("s_waitcnt lgkmcnt(0)" ::: "memory");
        __builtin_amdgcn_s_barrier();
        __builtin_amdgcn_sched_barrier(0);
        if (t + 1 < NN/64) { stageV(t + 1, 1); qk_phase(kbB, 1); }
        pv_phase(0);

        // odd sub-body: pv(t+1) on buffers 1
        const int u = t + 1;
        if (u + 2 < NN/64) loadKinto(u + 2, kbB);
        if (u < NN/64 - 2) asm volatile("s_waitcnt vmcnt(4)" ::: "memory");
        else               asm volatile("s_waitcnt vmcnt(0)" ::: "memory");
        asm volatile("s_waitcnt lgkmcnt(0)" ::: "memory");
        __builtin_amdgcn_s_barrier();
        __builtin_amdgcn_sched_barrier(0);
        if (u + 1 < NN/64) { stageV(u + 1, 0); qk_phase(kbA, 0); }
        pv_phase(1);
    }

    __syncthreads();                      // full drain before LDS reuse

    // ---- denominators (alias dead vlds as float scratch)
    float* sum_lds = (float*)&vlds[0][0];
    #pragma unroll
    for (int mq = 0; mq < 2; ++mq) {
        float v = ps[mq];
        v += __shfl_xor(v, 16, 64);
        v += __shfl_xor(v, 32, 64);
        if (lhi == 0) sum_lds[w*32 + mq*16 + llo] = v;
    }
    __syncthreads();

    const float gamma = gamma_p[0];
    float inv[4];
    #pragma unroll
    for (int mt = 0; mt < 4; ++mt) inv[mt] = 1.f / sum_lds[wc*64 + mt*16 + llo];

    #pragma unroll
    for (int et = 0; et < 8; ++et)
        #pragma unroll
        for (int mt = 0; mt < 4; ++mt) {
            const int m = m0 + wc*64 + mt*16 + llo;
            #pragma unroll
            for (int r = 0; r < 4; ++r) {
                const int e = eh*128 + et*16 + lhi*4 + r;
                size_t idx = ((size_t)(b*NC + e)) * NN + m;
                y[idx] = gamma * (acc[et][mt][r] * inv[mt]) + x[idx];
            }
        }
}

// ---------------------------------------------------------------------------
extern "C" void kernel_launch(void* const* d_in, const int* in_sizes, int n_in,
                              void* d_out, int out_size, void* d_ws, size_t ws_size,
                              hipStream_t stream) {
    const float* x     = (const float*)d_in[0];
    const float* Wq    = (const float*)d_in[1];
    const float* Wk    = (const float*)d_in[2];
    const float* Wv    = (const float*)d_in[3];
    const float* gamma = (const float*)d_in[4];
    float* y = (float*)d_out;

    bf16_t* Pqb = (bf16_t*)d_ws;
    bf16_t* Pkb = Pqb + (size_t)NB * NN * ND;
    bf16_t* Vnb = Pkb + (size_t)NB * NN * ND;
    bf16_t* Wb  = Vnb + (size_t)NB * NC * NN;
    bf16_t* Wlo = Wb  + 320 * 256;

    wconv<<<320, 256, 0, stream>>>(Wq, Wk, Wv, Wb, Wlo);
    proj_mfma<<<NB * (NN / BN_P), 512, 0, stream>>>(x, Wb, Wlo, Pqb, Pkb, Vnb);
    attn_mfma<<<NB * (NN/256), 512, 0, stream>>>(Pqb, Pkb, Vnb, x, gamma, y);
}

// Round 13
// 352.154 us; speedup vs baseline: 1.4798x; 1.4798x over previous
//
#include <hip/hip_runtime.h>
#include <math.h>
#include <stdint.h>

#define NB 16
#define NC 256
#define NN 4096
#define ND 32

typedef __bf16 bf16_t;
typedef __bf16 bf16x4 __attribute__((ext_vector_type(4)));
typedef __bf16 bf16x8 __attribute__((ext_vector_type(8)));
typedef float  f32x4  __attribute__((ext_vector_type(4)));

#define AS_GLOBAL __attribute__((address_space(1)))
#define AS_LDS    __attribute__((address_space(3)))

// ---------------------------------------------------------------------------
// Kernel 0: convert weights to bf16 (+ lo residuals for q/k rows).
// Wq rows pre-scaled by log2(e) so attention uses exp2 directly.
// ---------------------------------------------------------------------------
__global__ __launch_bounds__(256) void wconv(
    const float* __restrict__ Wq, const float* __restrict__ Wk,
    const float* __restrict__ Wv, bf16_t* __restrict__ Wb, bf16_t* __restrict__ Wlo)
{
    int i = blockIdx.x * 256 + threadIdx.x;
    if (i >= 320 * 256) return;
    int row = i >> 8, c = i & 255;
    float v;
    if (row < 256)      v = Wv[(row      ) * 256 + c];
    else if (row < 288) v = Wq[(row - 256) * 256 + c] * 1.44269504088896340736f;
    else                v = Wk[(row - 288) * 256 + c];
    bf16_t h = (bf16_t)v;
    Wb[i] = h;
    if (row >= 256) Wlo[(row - 256) * 256 + c] = (bf16_t)(v - (float)h);
}

// ---------------------------------------------------------------------------
// Kernel 1: fused q/k/v projection as one MFMA GEMM (unchanged, ~8 us).
// ---------------------------------------------------------------------------
#define BN_P  128
#define KSTEP 64
#define XPAD  130

__global__ __launch_bounds__(512) void proj_mfma(
    const float* __restrict__ x, const bf16_t* __restrict__ Wb,
    const bf16_t* __restrict__ Wlo,
    bf16_t* __restrict__ Pqb, bf16_t* __restrict__ Pkb, bf16_t* __restrict__ Vn)
{
    __shared__ float xt[KSTEP][XPAD];

    const int b  = blockIdx.x >> 5;
    const int n0 = (blockIdx.x & 31) * BN_P;
    const int tid  = threadIdx.x;
    const int lane = tid & 63;
    const int w    = tid >> 6;
    const int mstrip = w >> 1;
    const int nh     = w & 1;
    const int llo = lane & 15, lhi = lane >> 4;
    const bool qkwave = (mstrip == 3);

    const float* xb = x + (size_t)b * NC * NN + n0;

    f32x4 acc[5][4];
    #pragma unroll
    for (int mf = 0; mf < 5; ++mf)
        #pragma unroll
        for (int nf = 0; nf < 4; ++nf)
            acc[mf][nf] = (f32x4){0.f,0.f,0.f,0.f};

    for (int k0 = 0; k0 < NC; k0 += KSTEP) {
        #pragma unroll
        for (int p = 0; p < 4; ++p) {
            int idx = p * 512 + tid;
            int c   = idx >> 5;
            int nn  = (idx & 31) << 2;
            float4 v = *(const float4*)(xb + (size_t)(k0 + c) * NN + nn);
            *(float2*)&xt[c][nn]     = make_float2(v.x, v.y);
            *(float2*)&xt[c][nn + 2] = make_float2(v.z, v.w);
        }
        __syncthreads();

        #pragma unroll
        for (int ks = 0; ks < 2; ++ks) {
            bf16x8 Ah[5], Al[4];
            #pragma unroll
            for (int mf = 0; mf < 5; ++mf) {
                int row = mstrip * 80 + mf * 16 + llo;
                Ah[mf] = *(const bf16x8*)(Wb + (size_t)row * NC + k0 + ks * 32 + lhi * 8);
            }
            if (qkwave) {
                #pragma unroll
                for (int mf = 1; mf < 5; ++mf) {
                    int row = mstrip * 80 + mf * 16 + llo;
                    Al[mf-1] = *(const bf16x8*)(Wlo + (size_t)(row - 256) * NC
                                                + k0 + ks * 32 + lhi * 8);
                }
            }

            #pragma unroll
            for (int nf = 0; nf < 4; ++nf) {
                const int n  = nh * 64 + nf * 16 + llo;
                const int cb = ks * 32 + lhi * 8;
                bf16x8 bh, bl;
                #pragma unroll
                for (int j = 0; j < 8; ++j) {
                    float f = xt[cb + j][n];
                    bf16_t h = (bf16_t)f;
                    bh[j] = h;
                    if (qkwave) bl[j] = (bf16_t)(f - (float)h);
                }
                #pragma unroll
                for (int mf = 0; mf < 5; ++mf)
                    acc[mf][nf] = __builtin_amdgcn_mfma_f32_16x16x32_bf16(
                                      Ah[mf], bh, acc[mf][nf], 0, 0, 0);
                if (qkwave) {
                    #pragma unroll
                    for (int mf = 1; mf < 5; ++mf) {
                        acc[mf][nf] = __builtin_amdgcn_mfma_f32_16x16x32_bf16(
                                          Al[mf-1], bh, acc[mf][nf], 0, 0, 0);
                        acc[mf][nf] = __builtin_amdgcn_mfma_f32_16x16x32_bf16(
                                          Ah[mf], bl, acc[mf][nf], 0, 0, 0);
                    }
                }
            }
        }
        __syncthreads();
    }

    #pragma unroll
    for (int mf = 0; mf < 5; ++mf) {
        const int rowbase = mstrip * 80 + mf * 16 + lhi * 4;
        #pragma unroll
        for (int nf = 0; nf < 4; ++nf) {
            const int n = n0 + nh * 64 + nf * 16 + llo;
            if (rowbase < 256) {
                #pragma unroll
                for (int r = 0; r < 4; ++r)
                    Vn[((size_t)b * NC + rowbase + r) * NN + n] = (bf16_t)acc[mf][nf][r];
            } else {
                const int d = rowbase - 256;
                bf16x4 q4;
                #pragma unroll
                for (int r = 0; r < 4; ++r) q4[r] = (bf16_t)acc[mf][nf][r];
                if (d < 32) *(bf16x4*)(Pqb + ((size_t)b * NN + n) * ND + d) = q4;
                else        *(bf16x4*)(Pkb + ((size_t)b * NN + n) * ND + d - 32) = q4;
            }
        }
    }
}

// ---------------------------------------------------------------------------
// Kernel 2: GEMM-shaped attention (R9 schedule) + strength-reduced addressing.
// Block = (batch, 256-m chunk), 8 waves, 128 KB LDS, 1 block/CU.
// Step t: stageV(t+1) DMA -> vlds[nxt]; qk(t+1) -> plds[nxt]; loadK(t+2);
//         pv(t) from vlds/plds[cur]; __syncthreads().
// Loop unrolled x2 purely so buffer bases are loop-invariant; single kb[4];
// all global accesses go through running pointers += constant stride.
// K-load sequence: prologue K0,K1; even(t) loads K(t+2) [guard t<62];
// odd(t) loads K(t+3) [guard t<61 -> at t=60 loads K63; t=62 body skipped].
// ---------------------------------------------------------------------------
__global__ __launch_bounds__(512, 2) void attn_mfma(
    const bf16_t* __restrict__ Pqb,   // keys    K [B][N][32]
    const bf16_t* __restrict__ Pkb,   // queries Q [B][N][32] (pre-scaled log2e)
    const bf16_t* __restrict__ Vn,    // V [B][C][N]
    const float* __restrict__ x,
    const float* __restrict__ gamma_p,
    float* __restrict__ y)
{
    __shared__ bf16_t vlds[2][256*64];    // 64 KB V tiles, swizzled
    __shared__ bf16_t plds[2][256*64];    // 64 KB P tiles, swizzled

    const int wg  = blockIdx.x;
    const int swb = (wg & 7) * 32 + (wg >> 3);
    const int b   = swb >> 4;
    const int m0  = (swb & 15) << 8;

    const int tid  = threadIdx.x;
    const int lane = tid & 63;
    const int w    = tid >> 6;            // 0..7
    const int lhi  = lane >> 4;
    const int llo  = lane & 15;
    const int wc   = w & 3;               // PV m-quarter
    const int eh   = w >> 2;              // PV e-half

    // Q B-frags (hoisted)
    bf16x8 qa[2];
    #pragma unroll
    for (int mq = 0; mq < 2; ++mq)
        qa[mq] = *(const bf16x8*)(Pkb + ((size_t)(b*NN + m0 + w*32 + mq*16 + llo)) * ND + lhi*8);

    f32x4 acc[8][4];                      // [et][mt]
    #pragma unroll
    for (int et = 0; et < 8; ++et)
        #pragma unroll
        for (int mt = 0; mt < 4; ++mt)
            acc[et][mt] = (f32x4){0.f,0.f,0.f,0.f};

    float ps[2] = {0.f, 0.f};
    bf16x8 kb[4];
    const int swz = (llo & 7) << 4;

    // ---- running pointers (strength-reduced; += constant per tile)
    const bf16_t* kp = Pqb + (size_t)b * NN * ND + (size_t)llo * ND + lhi*8;
    const int r8  = lane >> 3;
    const int nsw = 8 * ((lane & 7) ^ r8);
    const bf16_t* Vball = Vn + (size_t)b * NC * NN;
    const bf16_t* vp0 = Vball + (size_t)(w*32 +  0 + r8) * NN + nsw;
    const bf16_t* vp1 = Vball + (size_t)(w*32 +  8 + r8) * NN + nsw;
    const bf16_t* vp2 = Vball + (size_t)(w*32 + 16 + r8) * NN + nsw;
    const bf16_t* vp3 = Vball + (size_t)(w*32 + 24 + r8) * NN + nsw;

    // loop-invariant LDS bases
    bf16_t* const vdst0[4] = { &vlds[0][(w*32)*64],      &vlds[0][(w*32+8)*64],
                               &vlds[0][(w*32+16)*64],   &vlds[0][(w*32+24)*64] };
    bf16_t* const vdst1[4] = { &vlds[1][(w*32)*64],      &vlds[1][(w*32+8)*64],
                               &vlds[1][(w*32+16)*64],   &vlds[1][(w*32+24)*64] };
    char* const pwb0 = (char*)&plds[0][0] + (size_t)(w*32 + llo) * 128;
    char* const pwb1 = (char*)&plds[1][0] + (size_t)(w*32 + llo) * 128;
    char* const vrb0 = (char*)&vlds[0][0];
    char* const vrb1 = (char*)&vlds[1][0];
    char* const prb0 = (char*)&plds[0][0];
    char* const prb1 = (char*)&plds[1][0];

    // K tile load: 4x dwordx4 at element offsets (16 rows = 512 elems);
    // advance 1 tile (64 rows = 2048 elems)
    auto loadK = [&]() {
        kb[0] = *(const bf16x8*)(kp);
        kb[1] = *(const bf16x8*)(kp + 512);
        kb[2] = *(const bf16x8*)(kp + 1024);
        kb[3] = *(const bf16x8*)(kp + 1536);
        kp += 2048;
    };

    // V DMA: 4x global_load_lds width 16; advance 1 tile (64 cols)
    auto stageV = [&](bf16_t* const* dst) {
        __builtin_amdgcn_global_load_lds((const AS_GLOBAL unsigned int*)vp0,
                                         (AS_LDS unsigned int*)dst[0], 16, 0, 0);
        __builtin_amdgcn_global_load_lds((const AS_GLOBAL unsigned int*)vp1,
                                         (AS_LDS unsigned int*)dst[1], 16, 0, 0);
        __builtin_amdgcn_global_load_lds((const AS_GLOBAL unsigned int*)vp2,
                                         (AS_LDS unsigned int*)dst[2], 16, 0, 0);
        __builtin_amdgcn_global_load_lds((const AS_GLOBAL unsigned int*)vp3,
                                         (AS_LDS unsigned int*)dst[3], 16, 0, 0);
        vp0 += 64; vp1 += 64; vp2 += 64; vp3 += 64;
    };

    auto qk_phase = [&](char* pwb) {
        f32x4 s[4][2];
        #pragma unroll
        for (int nt = 0; nt < 4; ++nt)
            #pragma unroll
            for (int mq = 0; mq < 2; ++mq)
                s[nt][mq] = __builtin_amdgcn_mfma_f32_16x16x32_bf16(kb[nt], qa[mq],
                                (f32x4){0.f,0.f,0.f,0.f}, 0, 0, 0);
        #pragma unroll
        for (int mq = 0; mq < 2; ++mq)
            #pragma unroll
            for (int nt = 0; nt < 4; ++nt) {
                bf16x4 q4;
                #pragma unroll
                for (int r = 0; r < 4; ++r) {
                    float p = __builtin_amdgcn_exp2f(s[nt][mq][r]);
                    ps[mq] += p;
                    q4[r] = (bf16_t)p;
                }
                *(bf16x4*)(pwb + mq*2048 + ((nt*32 + lhi*8) ^ swz)) = q4;
            }
    };

    auto pv_phase = [&](char* vb, char* pb) {
        #pragma unroll
        for (int ks = 0; ks < 2; ++ks) {
            const int cofs = (ks*64 + lhi*16) ^ swz;
            bf16x8 pf[4];
            #pragma unroll
            for (int mt = 0; mt < 4; ++mt)
                pf[mt] = *(const bf16x8*)(pb + (wc*64 + mt*16 + llo)*128 + cofs);
            bf16x8 va[8];
            #pragma unroll
            for (int ei = 0; ei < 8; ++ei)
                va[ei] = *(const bf16x8*)(vb + (eh*128 + ei*16 + llo)*128 + cofs);
            __builtin_amdgcn_s_setprio(1);
            #pragma unroll
            for (int ei = 0; ei < 8; ++ei)
                #pragma unroll
                for (int mt = 0; mt < 4; ++mt)
                    acc[ei][mt] = __builtin_amdgcn_mfma_f32_16x16x32_bf16(
                                      va[ei], pf[mt], acc[ei][mt], 0, 0, 0);
            __builtin_amdgcn_s_setprio(0);
        }
    };

    // ---- prologue: V(0) DMA, K(0), P(0) -> buf0, K(1)
    stageV(vdst0);
    loadK();                 // K(0)
    qk_phase(pwb0);          // P(0)
    loadK();                 // K(1)
    __syncthreads();

    // ---- main loop, unrolled x2 (static buffer bases, R9 schedule)
    for (int t = 0; t < NN/64; t += 2) {
        // even body: pv(t) on buffers 0; produce t+1 into buffers 1
        stageV(vdst1);                    // V(t+1)
        qk_phase(pwb1);                   // P(t+1), consumes kb = K(t+1)
        if (t < 62) loadK();              // K(t+2)
        pv_phase(vrb0, prb0);
        __syncthreads();

        // odd body: pv(t+1) on buffers 1; produce t+2 into buffers 0
        if (t < 62) {
            stageV(vdst0);                // V(t+2)
            qk_phase(pwb0);               // P(t+2), consumes kb = K(t+2)
            if (t < 61) loadK();          // K(t+3); at t=60 this loads K63
        }
        pv_phase(vrb1, prb1);
        __syncthreads();
    }

    // ---- denominators (alias dead vlds as float scratch)
    float* sum_lds = (float*)&vlds[0][0];
    #pragma unroll
    for (int mq = 0; mq < 2; ++mq) {
        float v = ps[mq];
        v += __shfl_xor(v, 16, 64);
        v += __shfl_xor(v, 32, 64);
        if (lhi == 0) sum_lds[w*32 + mq*16 + llo] = v;
    }
    __syncthreads();

    const float gamma = gamma_p[0];
    float inv[4];
    #pragma unroll
    for (int mt = 0; mt < 4; ++mt) inv[mt] = 1.f / sum_lds[wc*64 + mt*16 + llo];

    #pragma unroll
    for (int et = 0; et < 8; ++et)
        #pragma unroll
        for (int mt = 0; mt < 4; ++mt) {
            const int m = m0 + wc*64 + mt*16 + llo;
            #pragma unroll
            for (int r = 0; r < 4; ++r) {
                const int e = eh*128 + et*16 + lhi*4 + r;
                size_t idx = ((size_t)(b*NC + e)) * NN + m;
                y[idx] = gamma * (acc[et][mt][r] * inv[mt]) + x[idx];
            }
        }
}

// ---------------------------------------------------------------------------
extern "C" void kernel_launch(void* const* d_in, const int* in_sizes, int n_in,
                              void* d_out, int out_size, void* d_ws, size_t ws_size,
                              hipStream_t stream) {
    const float* x     = (const float*)d_in[0];
    const float* Wq    = (const float*)d_in[1];
    const float* Wk    = (const float*)d_in[2];
    const float* Wv    = (const float*)d_in[3];
    const float* gamma = (const float*)d_in[4];
    float* y = (float*)d_out;

    bf16_t* Pqb = (bf16_t*)d_ws;
    bf16_t* Pkb = Pqb + (size_t)NB * NN * ND;
    bf16_t* Vnb = Pkb + (size_t)NB * NN * ND;
    bf16_t* Wb  = Vnb + (size_t)NB * NC * NN;
    bf16_t* Wlo = Wb  + 320 * 256;

    wconv<<<320, 256, 0, stream>>>(Wq, Wk, Wv, Wb, Wlo);
    proj_mfma<<<NB * (NN / BN_P), 512, 0, stream>>>(x, Wb, Wlo, Pqb, Pkb, Vnb);
    attn_mfma<<<NB * (NN/256), 512, 0, stream>>>(Pqb, Pkb, Vnb, x, gamma, y);
}

// Round 14
// 200.829 us; speedup vs baseline: 2.5949x; 1.7535x over previous
//
#include <hip/hip_runtime.h>
#include <math.h>
#include <stdint.h>

#define NB 16
#define NC 256
#define NN 4096
#define ND 32

typedef __bf16 bf16_t;
typedef __bf16 bf16x4 __attribute__((ext_vector_type(4)));
typedef __bf16 bf16x8 __attribute__((ext_vector_type(8)));
typedef float  f32x4  __attribute__((ext_vector_type(4)));

#define AS_GLOBAL __attribute__((address_space(1)))
#define AS_LDS    __attribute__((address_space(3)))

// ---------------------------------------------------------------------------
// Kernel 0: convert weights to bf16 (+ lo residuals for q/k rows).
// Wq rows pre-scaled by log2(e) so attention uses exp2 directly.
// ---------------------------------------------------------------------------
__global__ __launch_bounds__(256) void wconv(
    const float* __restrict__ Wq, const float* __restrict__ Wk,
    const float* __restrict__ Wv, bf16_t* __restrict__ Wb, bf16_t* __restrict__ Wlo)
{
    int i = blockIdx.x * 256 + threadIdx.x;
    if (i >= 320 * 256) return;
    int row = i >> 8, c = i & 255;
    float v;
    if (row < 256)      v = Wv[(row      ) * 256 + c];
    else if (row < 288) v = Wq[(row - 256) * 256 + c] * 1.44269504088896340736f;
    else                v = Wk[(row - 288) * 256 + c];
    bf16_t h = (bf16_t)v;
    Wb[i] = h;
    if (row >= 256) Wlo[(row - 256) * 256 + c] = (bf16_t)(v - (float)h);
}

// ---------------------------------------------------------------------------
// Kernel 1: fused q/k/v projection as one MFMA GEMM (unchanged, ~8 us).
// ---------------------------------------------------------------------------
#define BN_P  128
#define KSTEP 64
#define XPAD  130

__global__ __launch_bounds__(512) void proj_mfma(
    const float* __restrict__ x, const bf16_t* __restrict__ Wb,
    const bf16_t* __restrict__ Wlo,
    bf16_t* __restrict__ Pqb, bf16_t* __restrict__ Pkb, bf16_t* __restrict__ Vn)
{
    __shared__ float xt[KSTEP][XPAD];

    const int b  = blockIdx.x >> 5;
    const int n0 = (blockIdx.x & 31) * BN_P;
    const int tid  = threadIdx.x;
    const int lane = tid & 63;
    const int w    = tid >> 6;
    const int mstrip = w >> 1;
    const int nh     = w & 1;
    const int llo = lane & 15, lhi = lane >> 4;
    const bool qkwave = (mstrip == 3);

    const float* xb = x + (size_t)b * NC * NN + n0;

    f32x4 acc[5][4];
    #pragma unroll
    for (int mf = 0; mf < 5; ++mf)
        #pragma unroll
        for (int nf = 0; nf < 4; ++nf)
            acc[mf][nf] = (f32x4){0.f,0.f,0.f,0.f};

    for (int k0 = 0; k0 < NC; k0 += KSTEP) {
        #pragma unroll
        for (int p = 0; p < 4; ++p) {
            int idx = p * 512 + tid;
            int c   = idx >> 5;
            int nn  = (idx & 31) << 2;
            float4 v = *(const float4*)(xb + (size_t)(k0 + c) * NN + nn);
            *(float2*)&xt[c][nn]     = make_float2(v.x, v.y);
            *(float2*)&xt[c][nn + 2] = make_float2(v.z, v.w);
        }
        __syncthreads();

        #pragma unroll
        for (int ks = 0; ks < 2; ++ks) {
            bf16x8 Ah[5], Al[4];
            #pragma unroll
            for (int mf = 0; mf < 5; ++mf) {
                int row = mstrip * 80 + mf * 16 + llo;
                Ah[mf] = *(const bf16x8*)(Wb + (size_t)row * NC + k0 + ks * 32 + lhi * 8);
            }
            if (qkwave) {
                #pragma unroll
                for (int mf = 1; mf < 5; ++mf) {
                    int row = mstrip * 80 + mf * 16 + llo;
                    Al[mf-1] = *(const bf16x8*)(Wlo + (size_t)(row - 256) * NC
                                                + k0 + ks * 32 + lhi * 8);
                }
            }

            #pragma unroll
            for (int nf = 0; nf < 4; ++nf) {
                const int n  = nh * 64 + nf * 16 + llo;
                const int cb = ks * 32 + lhi * 8;
                bf16x8 bh, bl;
                #pragma unroll
                for (int j = 0; j < 8; ++j) {
                    float f = xt[cb + j][n];
                    bf16_t h = (bf16_t)f;
                    bh[j] = h;
                    if (qkwave) bl[j] = (bf16_t)(f - (float)h);
                }
                #pragma unroll
                for (int mf = 0; mf < 5; ++mf)
                    acc[mf][nf] = __builtin_amdgcn_mfma_f32_16x16x32_bf16(
                                      Ah[mf], bh, acc[mf][nf], 0, 0, 0);
                if (qkwave) {
                    #pragma unroll
                    for (int mf = 1; mf < 5; ++mf) {
                        acc[mf][nf] = __builtin_amdgcn_mfma_f32_16x16x32_bf16(
                                          Al[mf-1], bh, acc[mf][nf], 0, 0, 0);
                        acc[mf][nf] = __builtin_amdgcn_mfma_f32_16x16x32_bf16(
                                          Ah[mf], bl, acc[mf][nf], 0, 0, 0);
                    }
                }
            }
        }
        __syncthreads();
    }

    #pragma unroll
    for (int mf = 0; mf < 5; ++mf) {
        const int rowbase = mstrip * 80 + mf * 16 + lhi * 4;
        #pragma unroll
        for (int nf = 0; nf < 4; ++nf) {
            const int n = n0 + nh * 64 + nf * 16 + llo;
            if (rowbase < 256) {
                #pragma unroll
                for (int r = 0; r < 4; ++r)
                    Vn[((size_t)b * NC + rowbase + r) * NN + n] = (bf16_t)acc[mf][nf][r];
            } else {
                const int d = rowbase - 256;
                bf16x4 q4;
                #pragma unroll
                for (int r = 0; r < 4; ++r) q4[r] = (bf16_t)acc[mf][nf][r];
                if (d < 32) *(bf16x4*)(Pqb + ((size_t)b * NN + n) * ND + d) = q4;
                else        *(bf16x4*)(Pkb + ((size_t)b * NN + n) * ND + d - 32) = q4;
            }
        }
    }
}

// ---------------------------------------------------------------------------
// Kernel 2: GEMM-shaped attention (R9 structure) with split-PV interleave.
// Block = (batch, 256-m chunk), 8 waves, 1 block/CU, 128 KB LDS.
// Step t: pv-ks0(t) | stageV(t+1)+qk(t+1) | loadK(t+2) | pv-ks1(t) | barrier.
// Producer phase sits between the two PV MFMA clusters so co-resident waves'
// VALU and MFMA windows tile instead of colliding in barrier lockstep.
// Buffer safety identical to R9: pv reads [cur], producers write [nxt],
// kb consumed (qk) before overwrite (loadK), one barrier per step.
// ---------------------------------------------------------------------------
__global__ __launch_bounds__(512, 2) void attn_mfma(
    const bf16_t* __restrict__ Pqb,   // keys    K [B][N][32]
    const bf16_t* __restrict__ Pkb,   // queries Q [B][N][32] (pre-scaled log2e)
    const bf16_t* __restrict__ Vn,    // V [B][C][N]
    const float* __restrict__ x,
    const float* __restrict__ gamma_p,
    float* __restrict__ y)
{
    __shared__ bf16_t vlds[2][256*64];    // 64 KB V tiles, swizzled
    __shared__ bf16_t plds[2][256*64];    // 64 KB P tiles, swizzled

    const int wg  = blockIdx.x;
    const int swb = (wg & 7) * 32 + (wg >> 3);
    const int b   = swb >> 4;
    const int m0  = (swb & 15) << 8;

    const int tid  = threadIdx.x;
    const int lane = tid & 63;
    const int w    = tid >> 6;            // 0..7
    const int lhi  = lane >> 4;
    const int llo  = lane & 15;
    const int wc   = w & 3;               // PV m-quarter
    const int eh   = w >> 2;              // PV e-half

    const bf16_t* Kbase = Pqb + (size_t)b * NN * ND;
    const bf16_t* Vball = Vn  + (size_t)b * NC * NN;

    bf16x8 qa[2];
    #pragma unroll
    for (int mq = 0; mq < 2; ++mq)
        qa[mq] = *(const bf16x8*)(Pkb + ((size_t)(b*NN + m0 + w*32 + mq*16 + llo)) * ND + lhi*8);

    f32x4 acc[8][4];                      // [et][mt]
    #pragma unroll
    for (int et = 0; et < 8; ++et)
        #pragma unroll
        for (int mt = 0; mt < 4; ++mt)
            acc[et][mt] = (f32x4){0.f,0.f,0.f,0.f};

    float ps[2] = {0.f, 0.f};
    bf16x8 kb[4];
    const int swz = (llo & 7) << 4;

    const int r8  = lane >> 3;
    const int nsw = 8 * ((lane & 7) ^ r8);
    auto stageV = [&](int tt, int bufw) {
        #pragma unroll
        for (int i = 0; i < 4; ++i) {
            const int row0 = w*32 + i*8;
            const bf16_t* src = Vball + (size_t)(row0 + r8) * NN + tt*64 + nsw;
            bf16_t* dst = &vlds[bufw][row0 * 64];
            __builtin_amdgcn_global_load_lds(
                (const AS_GLOBAL unsigned int*)src,
                (AS_LDS unsigned int*)dst, 16, 0, 0);
        }
    };

    auto loadK = [&](int tt) {
        #pragma unroll
        for (int nt = 0; nt < 4; ++nt)
            kb[nt] = *(const bf16x8*)(Kbase + (size_t)(tt*64 + nt*16 + llo) * ND + lhi*8);
    };

    auto qk_phase = [&](int bufw) {
        f32x4 s[4][2];
        #pragma unroll
        for (int nt = 0; nt < 4; ++nt)
            #pragma unroll
            for (int mq = 0; mq < 2; ++mq)
                s[nt][mq] = __builtin_amdgcn_mfma_f32_16x16x32_bf16(kb[nt], qa[mq],
                                (f32x4){0.f,0.f,0.f,0.f}, 0, 0, 0);
        char* base = (char*)&plds[bufw][0] + (size_t)(w*32 + llo) * 128;
        #pragma unroll
        for (int mq = 0; mq < 2; ++mq)
            #pragma unroll
            for (int nt = 0; nt < 4; ++nt) {
                bf16x4 q4;
                #pragma unroll
                for (int r = 0; r < 4; ++r) {
                    float p = __builtin_amdgcn_exp2f(s[nt][mq][r]);
                    ps[mq] += p;
                    q4[r] = (bf16_t)p;
                }
                *(bf16x4*)(base + mq*2048 + ((nt*32 + lhi*8) ^ swz)) = q4;
            }
    };

    // one ks-half of PV: 4 pf + 8 va ds_reads + 32 MFMA
    auto pv_ks = [&](int bufw, int ks) {
        char* vb = (char*)&vlds[bufw][0];
        char* pb = (char*)&plds[bufw][0];
        const int cofs = (ks*64 + lhi*16) ^ swz;
        bf16x8 pf[4];
        #pragma unroll
        for (int mt = 0; mt < 4; ++mt) {
            const int row = wc*64 + mt*16 + llo;
            pf[mt] = *(const bf16x8*)(pb + (size_t)row*128 + cofs);
        }
        bf16x8 va[8];
        #pragma unroll
        for (int ei = 0; ei < 8; ++ei) {
            const int row = eh*128 + ei*16 + llo;
            va[ei] = *(const bf16x8*)(vb + (size_t)row*128 + cofs);
        }
        __builtin_amdgcn_s_setprio(1);
        #pragma unroll
        for (int ei = 0; ei < 8; ++ei)
            #pragma unroll
            for (int mt = 0; mt < 4; ++mt)
                acc[ei][mt] = __builtin_amdgcn_mfma_f32_16x16x32_bf16(
                                  va[ei], pf[mt], acc[ei][mt], 0, 0, 0);
        __builtin_amdgcn_s_setprio(0);
    };

    // ---- prologue: V(0) DMA, K(0), P(0) -> buf0, K(1) in flight
    stageV(0, 0);
    loadK(0);
    qk_phase(0);
    loadK(1);
    __syncthreads();                      // V(0) + P(0) ready

    // ---- main loop: one barrier per step, producer phase between PV halves
    for (int t = 0; t < NN/64; ++t) {
        const int cur = t & 1;
        const int nxt = cur ^ 1;
        pv_ks(cur, 0);                    // first PV MFMA cluster
        if (t < NN/64 - 1) {
            stageV(t + 1, nxt);           // async DMA, drained at barrier
            qk_phase(nxt);                // kb holds K(t+1)
        }
        if (t < NN/64 - 2) loadK(t + 2);
        pv_ks(cur, 1);                    // second PV MFMA cluster
        __syncthreads();
    }

    // ---- denominators (alias dead vlds as float scratch)
    float* sum_lds = (float*)&vlds[0][0];
    #pragma unroll
    for (int mq = 0; mq < 2; ++mq) {
        float v = ps[mq];
        v += __shfl_xor(v, 16, 64);
        v += __shfl_xor(v, 32, 64);
        if (lhi == 0) sum_lds[w*32 + mq*16 + llo] = v;
    }
    __syncthreads();

    const float gamma = gamma_p[0];
    float inv[4];
    #pragma unroll
    for (int mt = 0; mt < 4; ++mt) inv[mt] = 1.f / sum_lds[wc*64 + mt*16 + llo];

    #pragma unroll
    for (int et = 0; et < 8; ++et)
        #pragma unroll
        for (int mt = 0; mt < 4; ++mt) {
            const int m = m0 + wc*64 + mt*16 + llo;
            #pragma unroll
            for (int r = 0; r < 4; ++r) {
                const int e = eh*128 + et*16 + lhi*4 + r;
                size_t idx = ((size_t)(b*NC + e)) * NN + m;
                y[idx] = gamma * (acc[et][mt][r] * inv[mt]) + x[idx];
            }
        }
}

// ---------------------------------------------------------------------------
extern "C" void kernel_launch(void* const* d_in, const int* in_sizes, int n_in,
                              void* d_out, int out_size, void* d_ws, size_t ws_size,
                              hipStream_t stream) {
    const float* x     = (const float*)d_in[0];
    const float* Wq    = (const float*)d_in[1];
    const float* Wk    = (const float*)d_in[2];
    const float* Wv    = (const float*)d_in[3];
    const float* gamma = (const float*)d_in[4];
    float* y = (float*)d_out;

    bf16_t* Pqb = (bf16_t*)d_ws;
    bf16_t* Pkb = Pqb + (size_t)NB * NN * ND;
    bf16_t* Vnb = Pkb + (size_t)NB * NN * ND;
    bf16_t* Wb  = Vnb + (size_t)NB * NC * NN;
    bf16_t* Wlo = Wb  + 320 * 256;

    wconv<<<320, 256, 0, stream>>>(Wq, Wk, Wv, Wb, Wlo);
    proj_mfma<<<NB * (NN / BN_P), 512, 0, stream>>>(x, Wb, Wlo, Pqb, Pkb, Vnb);
    attn_mfma<<<NB * (NN/256), 512, 0, stream>>>(Pqb, Pkb, Vnb, x, gamma, y);
}